// Round 6
// baseline (466.142 us; speedup 1.0000x reference)
//
#include <hip/hip_runtime.h>
#include <math.h>

#define S_LEN 2048
#define NHEADS 16
#define DK 64

typedef _Float16 h4 __attribute__((ext_vector_type(4)));
typedef _Float16 h8 __attribute__((ext_vector_type(8)));
typedef float f4 __attribute__((ext_vector_type(4)));

__device__ __forceinline__ void glds16(const void* g, void* l) {
  __builtin_amdgcn_global_load_lds(
      (const __attribute__((address_space(1))) unsigned int*)g,
      (__attribute__((address_space(3))) unsigned int*)l, 16, 0, 0);
}

// ------- fp32 -> f16 conversions (x + 4 weights) + RoPE table, one kernel ------
__global__ __launch_bounds__(256) void cvt_all(
    const float* __restrict__ x,
    const float* __restrict__ w0, const float* __restrict__ w1,
    const float* __restrict__ w2, const float* __restrict__ w3,
    _Float16* __restrict__ xh, _Float16* __restrict__ wh,
    const int* __restrict__ pos, float* __restrict__ sc) {
  int bid = blockIdx.x;
  if (bid < 8192) {
    int i = bid * 256 + threadIdx.x;
    float4 v = *(const float4*)(x + (size_t)i * 4);
    h4 o = {(_Float16)v.x, (_Float16)v.y, (_Float16)v.z, (_Float16)v.w};
    *(h4*)&xh[(size_t)i * 4] = o;
  } else if (bid < 12288) {
    int j = (bid - 8192) * 256 + threadIdx.x;
    const float* srcs[4] = {w0, w1, w2, w3};
    int which = j >> 18;
    int off = (j & 262143) * 4;
    float4 v = *(const float4*)(srcs[which] + off);
    // scale by 256 (exact pow2): keeps all weights in f16 normal range
    h4 o = {(_Float16)(v.x * 256.f), (_Float16)(v.y * 256.f),
            (_Float16)(v.z * 256.f), (_Float16)(v.w * 256.f)};
    *(h4*)&wh[(size_t)which * 1048576 + off] = o;
  } else {
    int idx = (bid - 12288) * 256 + threadIdx.x;  // 65536 = 2048 x 32
    int s = idx >> 5, p = idx & 31;
    double inv = pow(10000.0, -(double)(2 * p) / 64.0);
    double a = (double)pos[s] * inv;
    sc[s * 64 + 2 * p]     = (float)sin(a);
    sc[s * 64 + 2 * p + 1] = (float)cos(a);
  }
}

// ---------------- fused QKV GEMM: {Q,K,V} = x * W^T  (K = 1024) ----------------
// grid (24, 64): blockIdx.x -> {matrix 0..2} x {n-tile 0..7}; 128x128 tiles.
// Q/K: rope epilogue -> (B*H, S, 64); V: transposed -> (B*H, 64, S).
__global__ __launch_bounds__(256) void gemm_qkv(
    const _Float16* __restrict__ A, const _Float16* __restrict__ W3,
    _Float16* __restrict__ Qo, _Float16* __restrict__ Ko,
    _Float16* __restrict__ Vto, const float* __restrict__ sc_t) {
  __shared__ _Float16 As[128 * 32];
  __shared__ _Float16 Bs[128 * 32];
  const int t = threadIdx.x;
  const int lane = t & 63;
  const int w = t >> 6;
  const int mat = blockIdx.x >> 3;            // 0=Q 1=K 2=V
  const int n0 = (blockIdx.x & 7) * 128;
  const int m0 = blockIdx.y * 128;
  const _Float16* B = W3 + (size_t)mat * 1048576;
  const int wm = (w >> 1) * 64;
  const int wn = (w & 1) * 64;
  const int lm = lane & 15;
  const int kq = (lane >> 4) * 8;
  const int srow = lane >> 2;
  const int skof = (lane & 3) * 8;

  f4 acc[4][4];
#pragma unroll
  for (int i = 0; i < 4; i++)
#pragma unroll
    for (int j = 0; j < 4; j++) {
      f4 z = {0.f, 0.f, 0.f, 0.f};
      acc[i][j] = z;
    }

  for (int k0 = 0; k0 < 1024; k0 += 32) {
    __syncthreads();
#pragma unroll
    for (int c = 0; c < 2; c++) {
      int rr = (w + c * 4) * 16 + srow;
      glds16(A + (size_t)(m0 + rr) * 1024 + k0 + skof, (char*)As + (w + c * 4) * 1024);
      glds16(B + (size_t)(n0 + rr) * 1024 + k0 + skof, (char*)Bs + (w + c * 4) * 1024);
    }
    __syncthreads();

    h8 af[4], bf[4];
#pragma unroll
    for (int mt = 0; mt < 4; mt++)
      af[mt] = *(const h8*)(As + (wm + mt * 16 + lm) * 32 + kq);
#pragma unroll
    for (int nt = 0; nt < 4; nt++)
      bf[nt] = *(const h8*)(Bs + (wn + nt * 16 + lm) * 32 + kq);
#pragma unroll
    for (int mt = 0; mt < 4; mt++)
#pragma unroll
      for (int nt = 0; nt < 4; nt++)
        acc[mt][nt] = __builtin_amdgcn_mfma_f32_16x16x32_f16(af[mt], bf[nt],
                                                             acc[mt][nt], 0, 0, 0);
  }

  const float scale = 1.0f / 256.0f;
  const int quad = lane >> 4;
#pragma unroll
  for (int mt = 0; mt < 4; mt++) {
#pragma unroll
    for (int nt = 0; nt < 4; nt++) {
      int n = n0 + wn + nt * 16 + lm;
      int d = n & 63, h = n >> 6;
      int mbase = m0 + wm + mt * 16 + quad * 4;
      int s = mbase & (S_LEN - 1), b = mbase >> 11;
      if (mat == 2) {
        h4 ov = {(_Float16)(acc[mt][nt][0] * scale), (_Float16)(acc[mt][nt][1] * scale),
                 (_Float16)(acc[mt][nt][2] * scale), (_Float16)(acc[mt][nt][3] * scale)};
        *(h4*)&Vto[(((size_t)b * NHEADS + h) * DK + d) * S_LEN + s] = ov;
      } else {
        _Float16* C16 = (mat == 0) ? Qo : Ko;
        int p2 = d & ~1;
#pragma unroll
        for (int r = 0; r < 4; r++) {
          float v = acc[mt][nt][r] * scale;
          float2 sc = *(const float2*)&sc_t[(s + r) * 64 + p2];  // {sin, cos}
          float partner = __shfl_xor(v, 1);
          v = (d & 1) ? fmaf(v, sc.y, partner * sc.x)
                      : fmaf(v, sc.y, -partner * sc.x);
          C16[(((size_t)b * NHEADS + h) * S_LEN + (s + r)) * DK + d] = (_Float16)v;
        }
      }
    }
  }
}

// ---------------- output GEMM: out_f32 = AO * Wo^T -----------------------------
// 64x128 tile, grid (8,128) = 1024 blocks -> 4+ blocks/CU.
__global__ __launch_bounds__(256) void gemm_out(
    const _Float16* __restrict__ A, const _Float16* __restrict__ B,
    float* __restrict__ C32) {
  __shared__ _Float16 As[64 * 32];
  __shared__ _Float16 Bs[128 * 32];
  const int t = threadIdx.x;
  const int lane = t & 63;
  const int w = t >> 6;
  const int n0 = blockIdx.x * 128;
  const int m0 = blockIdx.y * 64;
  const int wm = (w >> 1) * 32;
  const int wn = (w & 1) * 64;
  const int lm = lane & 15;
  const int kq = (lane >> 4) * 8;
  const int srow = lane >> 2;
  const int skof = (lane & 3) * 8;

  f4 acc[2][4];
#pragma unroll
  for (int i = 0; i < 2; i++)
#pragma unroll
    for (int j = 0; j < 4; j++) {
      f4 z = {0.f, 0.f, 0.f, 0.f};
      acc[i][j] = z;
    }

  for (int k0 = 0; k0 < 1024; k0 += 32) {
    __syncthreads();
    glds16(A + (size_t)(m0 + w * 16 + srow) * 1024 + k0 + skof, (char*)As + w * 1024);
#pragma unroll
    for (int c = 0; c < 2; c++) {
      int rr = (w + c * 4) * 16 + srow;
      glds16(B + (size_t)(n0 + rr) * 1024 + k0 + skof, (char*)Bs + (w + c * 4) * 1024);
    }
    __syncthreads();

    h8 af[2], bf[4];
#pragma unroll
    for (int mt = 0; mt < 2; mt++)
      af[mt] = *(const h8*)(As + (wm + mt * 16 + lm) * 32 + kq);
#pragma unroll
    for (int nt = 0; nt < 4; nt++)
      bf[nt] = *(const h8*)(Bs + (wn + nt * 16 + lm) * 32 + kq);
#pragma unroll
    for (int mt = 0; mt < 2; mt++)
#pragma unroll
      for (int nt = 0; nt < 4; nt++)
        acc[mt][nt] = __builtin_amdgcn_mfma_f32_16x16x32_f16(af[mt], bf[nt],
                                                             acc[mt][nt], 0, 0, 0);
  }

  const float scale = 1.0f / 256.0f;
  const int quad = lane >> 4;
#pragma unroll
  for (int mt = 0; mt < 2; mt++)
#pragma unroll
    for (int nt = 0; nt < 4; nt++) {
      int n = n0 + wn + nt * 16 + lm;
#pragma unroll
      for (int r = 0; r < 4; r++) {
        int m = m0 + wm + mt * 16 + quad * 4 + r;
        C32[(size_t)m * 1024 + n] = acc[mt][nt][r] * scale;
      }
    }
}

// ---------------- MFMA causal flash attention ----------------------------------
// Q,K: (B*H, S, 64) f16.  Vt: (B*H, 64, S) f16.  O: (B, S, H*64) f16.
// 4 waves, Q-tile 128, KV-step 64. LDS 32KB via stride-64 + XOR-16B-unit
// swizzle (phys_unit = logical_unit ^ (row & 7)); all LDS addrs loop-invariant.
// __launch_bounds__(256,5): VGPR<=102 -> 5 blocks/CU (160KB LDS exactly).
__global__ __launch_bounds__(256, 5) void attn_mfma(
    const _Float16* __restrict__ Q, const _Float16* __restrict__ K,
    const _Float16* __restrict__ Vt, _Float16* __restrict__ O) {
  __shared__ _Float16 Ks[64 * 64];   // [s_k][d] swizzled
  __shared__ _Float16 Vs[64 * 64];   // [d][c]  swizzled
  __shared__ _Float16 Ps[128 * 64];  // [s_q][c] swizzled (wave-local bands)

  const int bh = blockIdx.x;
  const int qt = (gridDim.y - 1) - blockIdx.y;  // heavy tiles dispatch first
  const int q0 = qt * 128;
  const int t = threadIdx.x;
  const int lane = t & 63;
  const int w = t >> 6;
  const int lm = lane & 15;
  const int quad = lane >> 4;
  const int l7 = lm & 7;
  const size_t qkbase = (size_t)bh * S_LEN * DK;
  const size_t vbase  = (size_t)bh * DK * S_LEN;
  const int srow = t >> 2;
  const int scol = (t & 3) * 16;
  const int wq0 = q0 + w * 32;
  const f4 fzero = {0.f, 0.f, 0.f, 0.f};

  // staging LDS offsets (swizzled), loop-invariant
  const int r7 = srow & 7;
  const int su0 = ((t & 3) * 2) ^ r7;
  const int su1 = ((t & 3) * 2 + 1) ^ r7;
  const int st0 = srow * 64 + su0 * 8;
  const int st1 = srow * 64 + su1 * 8;

  // Q fragments in registers, pre-scaled by 1/sqrt(64)=0.125 (exact in f16)
  h8 qf[2][2];
#pragma unroll
  for (int nt = 0; nt < 2; nt++)
#pragma unroll
    for (int kc = 0; kc < 2; kc++) {
      h8 v = *(const h8*)(Q + qkbase + (size_t)(wq0 + nt * 16 + lm) * DK +
                          kc * 32 + quad * 8);
#pragma unroll
      for (int j = 0; j < 8; j++) v[j] = v[j] * (_Float16)0.125f;
      qf[nt][kc] = v;
    }

  f4 oacc[4][2];
#pragma unroll
  for (int mt = 0; mt < 4; mt++)
#pragma unroll
    for (int nt = 0; nt < 2; nt++) oacc[mt][nt] = fzero;
  float m_i[2] = {-INFINITY, -INFINITY};
  float l_i[2] = {0.f, 0.f};

  const int ktmax = 2 * qt + 1;
  const _Float16* kg = K + qkbase + (size_t)srow * DK + scol;
  const _Float16* vg = Vt + vbase + (size_t)srow * S_LEN + scol;
  h8 pk0 = *(const h8*)kg;
  h8 pk1 = *(const h8*)(kg + 8);
  h8 pv0 = *(const h8*)vg;
  h8 pv1 = *(const h8*)(vg + 8);

  for (int kt = 0; kt <= ktmax; kt++) {
    __syncthreads();  // barrier A: prior step's frag reads done
    *(h8*)&Ks[st0] = pk0;
    *(h8*)&Ks[st1] = pk1;
    *(h8*)&Vs[st0] = pv0;
    *(h8*)&Vs[st1] = pv1;
    if (kt < ktmax) {  // prefetch next tile; in flight through compute phase
      const _Float16* kgn = kg + (size_t)(kt + 1) * 64 * DK;
      const _Float16* vgn = vg + (kt + 1) * 64;
      pk0 = *(const h8*)kgn;
      pk1 = *(const h8*)(kgn + 8);
      pv0 = *(const h8*)vgn;
      pv1 = *(const h8*)(vgn + 8);
    }
    __syncthreads();  // barrier B: staging visible

    if (kt * 64 <= wq0 + 31) {  // wave-uniform: skip fully-masked tiles
      // S^T[c][s_q]: kc=0 initializes (mfma into fzero), kc=1 accumulates
      f4 s_[4][2];
      {
        h8 kf[4];
#pragma unroll
        for (int mt = 0; mt < 4; mt++)
          kf[mt] = *(const h8*)&Ks[(mt * 16 + lm) * 64 + (quad ^ l7) * 8];
#pragma unroll
        for (int mt = 0; mt < 4; mt++)
#pragma unroll
          for (int nt = 0; nt < 2; nt++)
            s_[mt][nt] = __builtin_amdgcn_mfma_f32_16x16x32_f16(kf[mt], qf[nt][0],
                                                                fzero, 0, 0, 0);
      }
      {
        h8 kf[4];
#pragma unroll
        for (int mt = 0; mt < 4; mt++)
          kf[mt] = *(const h8*)&Ks[(mt * 16 + lm) * 64 + ((4 + quad) ^ l7) * 8];
#pragma unroll
        for (int mt = 0; mt < 4; mt++)
#pragma unroll
          for (int nt = 0; nt < 2; nt++)
            s_[mt][nt] = __builtin_amdgcn_mfma_f32_16x16x32_f16(kf[mt], qf[nt][1],
                                                                s_[mt][nt], 0, 0, 0);
      }

      // causal mask (diagonal vicinity only; wave-uniform branch)
      if (kt * 64 + 63 > wq0) {
#pragma unroll
        for (int nt = 0; nt < 2; nt++) {
          int srq = wq0 + nt * 16 + lm;
#pragma unroll
          for (int mt = 0; mt < 4; mt++)
#pragma unroll
            for (int r = 0; r < 4; r++)
              if (kt * 64 + mt * 16 + quad * 4 + r > srq) s_[mt][nt][r] = -INFINITY;
        }
      }

      // online softmax; P -> LDS as f16 (wave-local band, no barrier needed)
#pragma unroll
      for (int nt = 0; nt < 2; nt++) {
        float mx = -INFINITY;
#pragma unroll
        for (int mt = 0; mt < 4; mt++)
#pragma unroll
          for (int r = 0; r < 4; r++) mx = fmaxf(mx, s_[mt][nt][r]);
        mx = fmaxf(mx, __shfl_xor(mx, 16));
        mx = fmaxf(mx, __shfl_xor(mx, 32));
        const bool grow = __any(mx > m_i[nt]);
        const float mnew = grow ? fmaxf(m_i[nt], mx) : m_i[nt];
        float sum = 0.f;
        const int prow = (w * 32 + nt * 16 + lm) * 64;
#pragma unroll
        for (int mt = 0; mt < 4; mt++) {
          float p0 = __expf(s_[mt][nt][0] - mnew);
          float p1 = __expf(s_[mt][nt][1] - mnew);
          float p2 = __expf(s_[mt][nt][2] - mnew);
          float p3 = __expf(s_[mt][nt][3] - mnew);
          sum += (p0 + p1) + (p2 + p3);
          h4 pv = {(_Float16)p0, (_Float16)p1, (_Float16)p2, (_Float16)p3};
          int pu = ((mt * 2 + (quad >> 1)) ^ l7) * 8 + (quad & 1) * 4;
          *(h4*)&Ps[prow + pu] = pv;
        }
        sum += __shfl_xor(sum, 16);
        sum += __shfl_xor(sum, 32);
        if (grow) {
          float alpha = __expf(m_i[nt] - mnew);
          m_i[nt] = mnew;
          l_i[nt] = fmaf(l_i[nt], alpha, sum);
#pragma unroll
          for (int mt = 0; mt < 4; mt++) {
            oacc[mt][nt][0] *= alpha; oacc[mt][nt][1] *= alpha;
            oacc[mt][nt][2] *= alpha; oacc[mt][nt][3] *= alpha;
          }
        } else {
          l_i[nt] += sum;
        }
      }

      // O^T += Vt_tile * P^T (P produced by this wave; in-order DS per wave)
#pragma unroll
      for (int kc = 0; kc < 2; kc++) {
        h8 vf[4], pf[2];
#pragma unroll
        for (int mt = 0; mt < 4; mt++)
          vf[mt] = *(const h8*)&Vs[(mt * 16 + lm) * 64 + ((kc * 4 + quad) ^ l7) * 8];
#pragma unroll
        for (int nt = 0; nt < 2; nt++)
          pf[nt] = *(const h8*)&Ps[(w * 32 + nt * 16 + lm) * 64 +
                                   ((kc * 4 + quad) ^ l7) * 8];
#pragma unroll
        for (int mt = 0; mt < 4; mt++)
#pragma unroll
          for (int nt = 0; nt < 2; nt++)
            oacc[mt][nt] = __builtin_amdgcn_mfma_f32_16x16x32_f16(vf[mt], pf[nt],
                                                                  oacc[mt][nt], 0, 0, 0);
      }
    }
  }

  // normalize + store O^T tiles: col = s_q (lane), rows = 4 consecutive d -> h4
  const int b = bh >> 4, head = bh & 15;
#pragma unroll
  for (int nt = 0; nt < 2; nt++) {
    float inv = 1.0f / l_i[nt];
    int s = wq0 + nt * 16 + lm;
#pragma unroll
    for (int mt = 0; mt < 4; mt++) {
      h4 ov = {(_Float16)(oacc[mt][nt][0] * inv), (_Float16)(oacc[mt][nt][1] * inv),
               (_Float16)(oacc[mt][nt][2] * inv), (_Float16)(oacc[mt][nt][3] * inv)};
      *(h4*)&O[((size_t)b * S_LEN + s) * 1024 + head * 64 + mt * 16 + quad * 4] = ov;
    }
  }
}

extern "C" void kernel_launch(void* const* d_in, const int* in_sizes, int n_in,
                              void* d_out, int out_size, void* d_ws, size_t ws_size,
                              hipStream_t stream) {
  const float* x   = (const float*)d_in[0];
  const int*   pos = (const int*)d_in[1];
  const float* Wq  = (const float*)d_in[2];
  const float* Wk  = (const float*)d_in[3];
  const float* Wv  = (const float*)d_in[4];
  const float* Wo  = (const float*)d_in[5];
  float* out = (float*)d_out;
  (void)in_sizes; (void)n_in; (void)out_size; (void)ws_size;

  const size_t NT = (size_t)4 * S_LEN * 1024;
  _Float16* q16  = (_Float16*)d_ws;
  _Float16* k16  = q16 + NT;
  _Float16* vt16 = k16 + NT;
  _Float16* aoh  = vt16 + NT;
  _Float16* xh   = aoh + NT;
  _Float16* wh   = xh + NT;                    // 4 x 1048576
  float* sc_t = (float*)(wh + 4 * 1048576);    // 2048 x 64 interleaved sin/cos

  cvt_all<<<12544, 256, 0, stream>>>(x, Wq, Wk, Wv, Wo, xh, wh, pos, sc_t);

  gemm_qkv<<<dim3(24, 64), 256, 0, stream>>>(xh, wh, q16, k16, vt16, sc_t);

  attn_mfma<<<dim3(64, S_LEN / 128), 256, 0, stream>>>(q16, k16, vt16, aoh);

  gemm_out<<<dim3(8, 128), 256, 0, stream>>>(aoh, wh + 3145728, out);
}

// Round 7
// 296.990 us; speedup vs baseline: 1.5696x; 1.5696x over previous
//
#include <hip/hip_runtime.h>
#include <math.h>

#define S_LEN 2048
#define NHEADS 16
#define DK 64

typedef _Float16 h4 __attribute__((ext_vector_type(4)));
typedef _Float16 h8 __attribute__((ext_vector_type(8)));
typedef float f4 __attribute__((ext_vector_type(4)));

__device__ __forceinline__ void glds16(const void* g, void* l) {
  __builtin_amdgcn_global_load_lds(
      (const __attribute__((address_space(1))) unsigned int*)g,
      (__attribute__((address_space(3))) unsigned int*)l, 16, 0, 0);
}

// ------- fp32 -> f16 conversions (x + 4 weights) + RoPE table, one kernel ------
__global__ __launch_bounds__(256) void cvt_all(
    const float* __restrict__ x,
    const float* __restrict__ w0, const float* __restrict__ w1,
    const float* __restrict__ w2, const float* __restrict__ w3,
    _Float16* __restrict__ xh, _Float16* __restrict__ wh,
    const int* __restrict__ pos, float* __restrict__ sc) {
  int bid = blockIdx.x;
  if (bid < 8192) {
    int i = bid * 256 + threadIdx.x;
    float4 v = *(const float4*)(x + (size_t)i * 4);
    h4 o = {(_Float16)v.x, (_Float16)v.y, (_Float16)v.z, (_Float16)v.w};
    *(h4*)&xh[(size_t)i * 4] = o;
  } else if (bid < 12288) {
    int j = (bid - 8192) * 256 + threadIdx.x;
    const float* srcs[4] = {w0, w1, w2, w3};
    int which = j >> 18;
    int off = (j & 262143) * 4;
    float4 v = *(const float4*)(srcs[which] + off);
    // scale by 256 (exact pow2): keeps all weights in f16 normal range
    h4 o = {(_Float16)(v.x * 256.f), (_Float16)(v.y * 256.f),
            (_Float16)(v.z * 256.f), (_Float16)(v.w * 256.f)};
    *(h4*)&wh[(size_t)which * 1048576 + off] = o;
  } else {
    int idx = (bid - 12288) * 256 + threadIdx.x;  // 65536 = 2048 x 32
    int s = idx >> 5, p = idx & 31;
    double inv = pow(10000.0, -(double)(2 * p) / 64.0);
    double a = (double)pos[s] * inv;
    sc[s * 64 + 2 * p]     = (float)sin(a);
    sc[s * 64 + 2 * p + 1] = (float)cos(a);
  }
}

// ---------------- fused QKV GEMM: {Q,K,V} = x * W^T  (K = 1024) ----------------
// grid (24, 64): blockIdx.x -> {matrix 0..2} x {n-tile 0..7}; 128x128 tiles.
// Q/K: rope epilogue -> (B*H, S, 64); V: transposed -> (B*H, 64, S).
__global__ __launch_bounds__(256) void gemm_qkv(
    const _Float16* __restrict__ A, const _Float16* __restrict__ W3,
    _Float16* __restrict__ Qo, _Float16* __restrict__ Ko,
    _Float16* __restrict__ Vto, const float* __restrict__ sc_t) {
  __shared__ _Float16 As[128 * 32];
  __shared__ _Float16 Bs[128 * 32];
  const int t = threadIdx.x;
  const int lane = t & 63;
  const int w = t >> 6;
  const int mat = blockIdx.x >> 3;            // 0=Q 1=K 2=V
  const int n0 = (blockIdx.x & 7) * 128;
  const int m0 = blockIdx.y * 128;
  const _Float16* B = W3 + (size_t)mat * 1048576;
  const int wm = (w >> 1) * 64;
  const int wn = (w & 1) * 64;
  const int lm = lane & 15;
  const int kq = (lane >> 4) * 8;
  const int srow = lane >> 2;
  const int skof = (lane & 3) * 8;

  f4 acc[4][4];
#pragma unroll
  for (int i = 0; i < 4; i++)
#pragma unroll
    for (int j = 0; j < 4; j++) {
      f4 z = {0.f, 0.f, 0.f, 0.f};
      acc[i][j] = z;
    }

  for (int k0 = 0; k0 < 1024; k0 += 32) {
    __syncthreads();
#pragma unroll
    for (int c = 0; c < 2; c++) {
      int rr = (w + c * 4) * 16 + srow;
      glds16(A + (size_t)(m0 + rr) * 1024 + k0 + skof, (char*)As + (w + c * 4) * 1024);
      glds16(B + (size_t)(n0 + rr) * 1024 + k0 + skof, (char*)Bs + (w + c * 4) * 1024);
    }
    __syncthreads();

    h8 af[4], bf[4];
#pragma unroll
    for (int mt = 0; mt < 4; mt++)
      af[mt] = *(const h8*)(As + (wm + mt * 16 + lm) * 32 + kq);
#pragma unroll
    for (int nt = 0; nt < 4; nt++)
      bf[nt] = *(const h8*)(Bs + (wn + nt * 16 + lm) * 32 + kq);
#pragma unroll
    for (int mt = 0; mt < 4; mt++)
#pragma unroll
      for (int nt = 0; nt < 4; nt++)
        acc[mt][nt] = __builtin_amdgcn_mfma_f32_16x16x32_f16(af[mt], bf[nt],
                                                             acc[mt][nt], 0, 0, 0);
  }

  const float scale = 1.0f / 256.0f;
  const int quad = lane >> 4;
#pragma unroll
  for (int mt = 0; mt < 4; mt++) {
#pragma unroll
    for (int nt = 0; nt < 4; nt++) {
      int n = n0 + wn + nt * 16 + lm;
      int d = n & 63, h = n >> 6;
      int mbase = m0 + wm + mt * 16 + quad * 4;
      int s = mbase & (S_LEN - 1), b = mbase >> 11;
      if (mat == 2) {
        h4 ov = {(_Float16)(acc[mt][nt][0] * scale), (_Float16)(acc[mt][nt][1] * scale),
                 (_Float16)(acc[mt][nt][2] * scale), (_Float16)(acc[mt][nt][3] * scale)};
        *(h4*)&Vto[(((size_t)b * NHEADS + h) * DK + d) * S_LEN + s] = ov;
      } else {
        _Float16* C16 = (mat == 0) ? Qo : Ko;
        int p2 = d & ~1;
#pragma unroll
        for (int r = 0; r < 4; r++) {
          float v = acc[mt][nt][r] * scale;
          float2 sc = *(const float2*)&sc_t[(s + r) * 64 + p2];  // {sin, cos}
          float partner = __shfl_xor(v, 1);
          v = (d & 1) ? fmaf(v, sc.y, partner * sc.x)
                      : fmaf(v, sc.y, -partner * sc.x);
          C16[(((size_t)b * NHEADS + h) * S_LEN + (s + r)) * DK + d] = (_Float16)v;
        }
      }
    }
  }
}

// ---------------- output GEMM: out_f32 = AO * Wo^T -----------------------------
// 64x128 tile, grid (8,128) = 1024 blocks -> 4+ blocks/CU.
__global__ __launch_bounds__(256) void gemm_out(
    const _Float16* __restrict__ A, const _Float16* __restrict__ B,
    float* __restrict__ C32) {
  __shared__ _Float16 As[64 * 32];
  __shared__ _Float16 Bs[128 * 32];
  const int t = threadIdx.x;
  const int lane = t & 63;
  const int w = t >> 6;
  const int n0 = blockIdx.x * 128;
  const int m0 = blockIdx.y * 64;
  const int wm = (w >> 1) * 32;
  const int wn = (w & 1) * 64;
  const int lm = lane & 15;
  const int kq = (lane >> 4) * 8;
  const int srow = lane >> 2;
  const int skof = (lane & 3) * 8;

  f4 acc[2][4];
#pragma unroll
  for (int i = 0; i < 2; i++)
#pragma unroll
    for (int j = 0; j < 4; j++) {
      f4 z = {0.f, 0.f, 0.f, 0.f};
      acc[i][j] = z;
    }

  for (int k0 = 0; k0 < 1024; k0 += 32) {
    __syncthreads();
    glds16(A + (size_t)(m0 + w * 16 + srow) * 1024 + k0 + skof, (char*)As + w * 1024);
#pragma unroll
    for (int c = 0; c < 2; c++) {
      int rr = (w + c * 4) * 16 + srow;
      glds16(B + (size_t)(n0 + rr) * 1024 + k0 + skof, (char*)Bs + (w + c * 4) * 1024);
    }
    __syncthreads();

    h8 af[2], bf[4];
#pragma unroll
    for (int mt = 0; mt < 2; mt++)
      af[mt] = *(const h8*)(As + (wm + mt * 16 + lm) * 32 + kq);
#pragma unroll
    for (int nt = 0; nt < 4; nt++)
      bf[nt] = *(const h8*)(Bs + (wn + nt * 16 + lm) * 32 + kq);
#pragma unroll
    for (int mt = 0; mt < 2; mt++)
#pragma unroll
      for (int nt = 0; nt < 4; nt++)
        acc[mt][nt] = __builtin_amdgcn_mfma_f32_16x16x32_f16(af[mt], bf[nt],
                                                             acc[mt][nt], 0, 0, 0);
  }

  const float scale = 1.0f / 256.0f;
  const int quad = lane >> 4;
#pragma unroll
  for (int mt = 0; mt < 2; mt++)
#pragma unroll
    for (int nt = 0; nt < 4; nt++) {
      int n = n0 + wn + nt * 16 + lm;
#pragma unroll
      for (int r = 0; r < 4; r++) {
        int m = m0 + wm + mt * 16 + quad * 4 + r;
        C32[(size_t)m * 1024 + n] = acc[mt][nt][r] * scale;
      }
    }
}

// ---------------- MFMA causal flash attention ----------------------------------
// Q,K: (B*H, S, 64) f16.  Vt: (B*H, 64, S) f16.  O: (B, S, H*64) f16.
// 4 waves, Q-tile 128 (wave owns 32 q-rows), KV-step 64. 2 barriers/step,
// register prefetch of next K/V tile, wave-local P, skip-rescale.
// Softmax in exp2 domain: log2(e) folded into the Q pre-scale (uniform
// temperature perturbation ~2e-4 -> <1e-5 on final out), exp2f = bare v_exp_f32.
// NOTE: do NOT force occupancy via __launch_bounds__ 2nd arg — round 6 showed
// the allocator spills off a cliff (VGPR 104->48, 600 MB scratch traffic).
__global__ __launch_bounds__(256) void attn_mfma(
    const _Float16* __restrict__ Q, const _Float16* __restrict__ K,
    const _Float16* __restrict__ Vt, _Float16* __restrict__ O) {
  __shared__ _Float16 Ks[64 * 72];   // [s_k][d] stride 72
  __shared__ _Float16 Vs[64 * 72];   // [d][c]  stride 72
  __shared__ _Float16 Ps[128 * 72];  // [s_q][c] stride 72 (wave-local bands)

  const int bh = blockIdx.x;
  const int qt = (gridDim.y - 1) - blockIdx.y;  // heavy tiles dispatch first
  const int q0 = qt * 128;
  const int t = threadIdx.x;
  const int lane = t & 63;
  const int w = t >> 6;
  const int lm = lane & 15;
  const int quad = lane >> 4;
  const size_t qkbase = (size_t)bh * S_LEN * DK;
  const size_t vbase  = (size_t)bh * DK * S_LEN;
  const int srow = t >> 2;
  const int scol = (t & 3) * 16;
  const int wq0 = q0 + w * 32;

  // Q fragments in registers, pre-scaled by log2(e)/sqrt(64) (exp2-domain scores)
  const _Float16 qscale = (_Float16)(0.125f * 1.44269504f);
  h8 qf[2][2];
#pragma unroll
  for (int nt = 0; nt < 2; nt++)
#pragma unroll
    for (int kc = 0; kc < 2; kc++) {
      h8 v = *(const h8*)(Q + qkbase + (size_t)(wq0 + nt * 16 + lm) * DK +
                          kc * 32 + quad * 8);
#pragma unroll
      for (int j = 0; j < 8; j++) v[j] = v[j] * qscale;
      qf[nt][kc] = v;
    }

  f4 oacc[4][2];
#pragma unroll
  for (int mt = 0; mt < 4; mt++)
#pragma unroll
    for (int nt = 0; nt < 2; nt++) {
      f4 z = {0.f, 0.f, 0.f, 0.f};
      oacc[mt][nt] = z;
    }
  float m_i[2] = {-INFINITY, -INFINITY};
  float l_i[2] = {0.f, 0.f};

  const int ktmax = 2 * qt + 1;
  const _Float16* kg = K + qkbase + (size_t)srow * DK + scol;
  const _Float16* vg = Vt + vbase + (size_t)srow * S_LEN + scol;
  h8 pk0 = *(const h8*)kg;
  h8 pk1 = *(const h8*)(kg + 8);
  h8 pv0 = *(const h8*)vg;
  h8 pv1 = *(const h8*)(vg + 8);

  for (int kt = 0; kt <= ktmax; kt++) {
    __syncthreads();  // barrier A: prior step's frag reads done
    *(h8*)&Ks[srow * 72 + scol] = pk0;
    *(h8*)&Ks[srow * 72 + scol + 8] = pk1;
    *(h8*)&Vs[srow * 72 + scol] = pv0;
    *(h8*)&Vs[srow * 72 + scol + 8] = pv1;
    if (kt < ktmax) {  // prefetch next tile; in flight through compute phase
      const _Float16* kgn = kg + (size_t)(kt + 1) * 64 * DK;
      const _Float16* vgn = vg + (kt + 1) * 64;
      pk0 = *(const h8*)kgn;
      pk1 = *(const h8*)(kgn + 8);
      pv0 = *(const h8*)vgn;
      pv1 = *(const h8*)(vgn + 8);
    }
    __syncthreads();  // barrier B: staging visible

    if (kt * 64 <= wq0 + 31) {  // wave-uniform: skip fully-masked tiles
      // S^T[c][s_q]
      f4 s_[4][2];
#pragma unroll
      for (int mt = 0; mt < 4; mt++)
#pragma unroll
        for (int nt = 0; nt < 2; nt++) {
          f4 z = {0.f, 0.f, 0.f, 0.f};
          s_[mt][nt] = z;
        }
#pragma unroll
      for (int kc = 0; kc < 2; kc++) {
        h8 kf[4];
#pragma unroll
        for (int mt = 0; mt < 4; mt++)
          kf[mt] = *(const h8*)&Ks[(mt * 16 + lm) * 72 + kc * 32 + quad * 8];
#pragma unroll
        for (int mt = 0; mt < 4; mt++)
#pragma unroll
          for (int nt = 0; nt < 2; nt++)
            s_[mt][nt] = __builtin_amdgcn_mfma_f32_16x16x32_f16(kf[mt], qf[nt][kc],
                                                                s_[mt][nt], 0, 0, 0);
      }

      // causal mask (diagonal vicinity only; wave-uniform branch)
      if (kt * 64 + 63 > wq0) {
#pragma unroll
        for (int nt = 0; nt < 2; nt++) {
          int srq = wq0 + nt * 16 + lm;
#pragma unroll
          for (int mt = 0; mt < 4; mt++)
#pragma unroll
            for (int r = 0; r < 4; r++)
              if (kt * 64 + mt * 16 + quad * 4 + r > srq) s_[mt][nt][r] = -INFINITY;
        }
      }

      // online softmax (exp2 domain); P -> LDS as f16 (wave-local band)
#pragma unroll
      for (int nt = 0; nt < 2; nt++) {
        float mx = -INFINITY;
#pragma unroll
        for (int mt = 0; mt < 4; mt++)
#pragma unroll
          for (int r = 0; r < 4; r++) mx = fmaxf(mx, s_[mt][nt][r]);
        mx = fmaxf(mx, __shfl_xor(mx, 16));
        mx = fmaxf(mx, __shfl_xor(mx, 32));
        const bool grow = __any(mx > m_i[nt]);
        const float mnew = grow ? fmaxf(m_i[nt], mx) : m_i[nt];
        float sum = 0.f;
#pragma unroll
        for (int mt = 0; mt < 4; mt++) {
          float p0 = exp2f(s_[mt][nt][0] - mnew);
          float p1 = exp2f(s_[mt][nt][1] - mnew);
          float p2 = exp2f(s_[mt][nt][2] - mnew);
          float p3 = exp2f(s_[mt][nt][3] - mnew);
          sum += (p0 + p1) + (p2 + p3);
          h4 pv = {(_Float16)p0, (_Float16)p1, (_Float16)p2, (_Float16)p3};
          *(h4*)&Ps[(w * 32 + nt * 16 + lm) * 72 + mt * 16 + quad * 4] = pv;
        }
        sum += __shfl_xor(sum, 16);
        sum += __shfl_xor(sum, 32);
        if (grow) {
          float alpha = exp2f(m_i[nt] - mnew);
          m_i[nt] = mnew;
          l_i[nt] = fmaf(l_i[nt], alpha, sum);
#pragma unroll
          for (int mt = 0; mt < 4; mt++) {
            oacc[mt][nt][0] *= alpha; oacc[mt][nt][1] *= alpha;
            oacc[mt][nt][2] *= alpha; oacc[mt][nt][3] *= alpha;
          }
        } else {
          l_i[nt] += sum;
        }
      }

      // O^T += Vt_tile * P^T (P produced by this wave; in-order DS per wave)
#pragma unroll
      for (int kc = 0; kc < 2; kc++) {
        h8 vf[4], pf[2];
#pragma unroll
        for (int mt = 0; mt < 4; mt++)
          vf[mt] = *(const h8*)&Vs[(mt * 16 + lm) * 72 + kc * 32 + quad * 8];
#pragma unroll
        for (int nt = 0; nt < 2; nt++)
          pf[nt] = *(const h8*)&Ps[(w * 32 + nt * 16 + lm) * 72 + kc * 32 + quad * 8];
#pragma unroll
        for (int mt = 0; mt < 4; mt++)
#pragma unroll
          for (int nt = 0; nt < 2; nt++)
            oacc[mt][nt] = __builtin_amdgcn_mfma_f32_16x16x32_f16(vf[mt], pf[nt],
                                                                  oacc[mt][nt], 0, 0, 0);
      }
    }
  }

  // normalize + store O^T tiles: col = s_q (lane), rows = 4 consecutive d -> h4
  const int b = bh >> 4, head = bh & 15;
#pragma unroll
  for (int nt = 0; nt < 2; nt++) {
    float inv = 1.0f / l_i[nt];
    int s = wq0 + nt * 16 + lm;
#pragma unroll
    for (int mt = 0; mt < 4; mt++) {
      h4 ov = {(_Float16)(oacc[mt][nt][0] * inv), (_Float16)(oacc[mt][nt][1] * inv),
               (_Float16)(oacc[mt][nt][2] * inv), (_Float16)(oacc[mt][nt][3] * inv)};
      *(h4*)&O[((size_t)b * S_LEN + s) * 1024 + head * 64 + mt * 16 + quad * 4] = ov;
    }
  }
}

extern "C" void kernel_launch(void* const* d_in, const int* in_sizes, int n_in,
                              void* d_out, int out_size, void* d_ws, size_t ws_size,
                              hipStream_t stream) {
  const float* x   = (const float*)d_in[0];
  const int*   pos = (const int*)d_in[1];
  const float* Wq  = (const float*)d_in[2];
  const float* Wk  = (const float*)d_in[3];
  const float* Wv  = (const float*)d_in[4];
  const float* Wo  = (const float*)d_in[5];
  float* out = (float*)d_out;
  (void)in_sizes; (void)n_in; (void)out_size; (void)ws_size;

  const size_t NT = (size_t)4 * S_LEN * 1024;
  _Float16* q16  = (_Float16*)d_ws;
  _Float16* k16  = q16 + NT;
  _Float16* vt16 = k16 + NT;
  _Float16* aoh  = vt16 + NT;
  _Float16* xh   = aoh + NT;
  _Float16* wh   = xh + NT;                    // 4 x 1048576
  float* sc_t = (float*)(wh + 4 * 1048576);    // 2048 x 64 interleaved sin/cos

  cvt_all<<<12544, 256, 0, stream>>>(x, Wq, Wk, Wv, Wo, xh, wh, pos, sc_t);

  gemm_qkv<<<dim3(24, 64), 256, 0, stream>>>(xh, wh, q16, k16, vt16, sc_t);

  attn_mfma<<<dim3(64, S_LEN / 128), 256, 0, stream>>>(q16, k16, vt16, aoh);

  gemm_out<<<dim3(8, 128), 256, 0, stream>>>(aoh, wh + 3145728, out);
}